// Round 10
// baseline (1483.606 us; speedup 1.0000x reference)
//
#include <hip/hip_runtime.h>
#include <hip/hip_bf16.h>

#define FEAT 128
#define OUTF 64
#define BCAP 6144   // bucket capacity; mean 4096, sigma ~64 -> +32 sigma, cannot overflow

typedef __attribute__((ext_vector_type(8))) short short8;   // 8 bf16 = 4 VGPRs (MFMA A/B frag)
typedef __attribute__((ext_vector_type(4))) float floatx4;  // MFMA C/D frag

// ---- bf16 helpers (packed pair in a 32-bit word, little-endian: lo16 = even elem) ----
__device__ inline float bflo(unsigned p) { union { unsigned u; float f; } c; c.u = p << 16;        return c.f; }
__device__ inline float bfhi(unsigned p) { union { unsigned u; float f; } c; c.u = p & 0xffff0000u; return c.f; }
__device__ inline unsigned rne16(float v) {   // fp32 -> bf16 bits, round-nearest-even
    union { float f; unsigned u; } c; c.f = v;
    return (c.u + 0x7fffu + ((c.u >> 16) & 1u)) >> 16;
}
__device__ inline unsigned pack2bf(float a, float b) { return rne16(a) | (rne16(b) << 16); }

// ---------------- dtype sniffing ----------------
// flags[0]=1 iff x is packed bf16; flags[1]=1 iff edge_index is int64; flags[2]=1 iff W is packed bf16.
// Established world (R0-R9): x fp32, W bf16, out fp32. Sniffs kept for robustness.
__global__ void sniff(const unsigned* __restrict__ x, const unsigned* __restrict__ ei,
                      const unsigned* __restrict__ Wv, int* __restrict__ flags) {
    __shared__ int s_x, s_z, s_w;
    if (threadIdx.x == 0) { s_x = 0; s_z = 0; s_w = 0; }
    __syncthreads();
    unsigned lx = x[threadIdx.x] & 0xffffu;
    unsigned ex = (lx >> 7) & 0xffu;
    if (lx == 0u || (ex >= 100u && ex <= 140u)) atomicAdd(&s_x, 1);
    unsigned lw = Wv[threadIdx.x] & 0xffffu;
    unsigned ew = (lw >> 7) & 0xffu;
    if (lw == 0u || (ew >= 100u && ew <= 140u)) atomicAdd(&s_w, 1);
    if (ei[2 * threadIdx.x + 1] == 0u) atomicAdd(&s_z, 1);
    __syncthreads();
    if (threadIdx.x == 0) {
        flags[0] = (s_x >= 230) ? 1 : 0;
        flags[1] = (s_z >= 250) ? 1 : 0;
        flags[2] = (s_w >= 230) ? 1 : 0;
    }
}

__device__ inline int edge_row(const int* __restrict__ ei, int E, int e, int w64) {
    return w64 ? ei[2 * e] : ei[e];
}
__device__ inline int edge_col(const int* __restrict__ ei, int E, int e, int w64) {
    return w64 ? ei[2 * (E + e)] : ei[E + e];
}

// ---------------- CSR build: two-level bucket sort ----------------
// R9 post-mortem: one-shot random 4B scatter = 107MB HBM writes (64B-line amplification,
// 115us) + count_in random atomics. Replace with dense bucketed writes.

__global__ void zero_buckets(int* __restrict__ bcnt, int* __restrict__ bcursor, int nbuck) {
    int i = blockIdx.x * blockDim.x + threadIdx.x;
    if (i < nbuck) { bcnt[i] = 0; bcursor[i] = 0; }
}

__global__ void bucket_count(const int* __restrict__ ei, int E, int* __restrict__ bcnt,
                             const int* __restrict__ flags) {
    int e = blockIdx.x * blockDim.x + threadIdx.x;
    if (e < E) atomicAdd(&bcnt[edge_col(ei, E, e, flags[1]) >> 8], 1);
}

// single block: exclusive scan of nb (<=512) bucket counts; total -> offsets[n]
__global__ void scan_bsums(const int* __restrict__ bsum, int nb,
                           int* __restrict__ boff, int* __restrict__ total_out) {
    __shared__ int sdata[512];
    int tid = threadIdx.x;
    int v = (tid < nb) ? bsum[tid] : 0;
    sdata[tid] = v;
    __syncthreads();
    for (int off = 1; off < 512; off <<= 1) {
        int t = (tid >= off) ? sdata[tid - off] : 0;
        __syncthreads();
        sdata[tid] += t;
        __syncthreads();
    }
    if (tid < nb) boff[tid] = sdata[tid] - v;       // exclusive
    if (tid == 511) *total_out = sdata[511];        // grand total -> offsets[n]
}

// dense ticketed append: bucket[b*BCAP + t] = (local_node << 20) | src_row
__global__ void bucket_scatter(const int* __restrict__ ei, int E,
                               int* __restrict__ bcursor, unsigned* __restrict__ bucket,
                               const int* __restrict__ flags) {
    int e = blockIdx.x * blockDim.x + threadIdx.x;
    if (e < E) {
        int w64 = flags[1];
        int c = edge_col(ei, E, e, w64);
        int r = edge_row(ei, E, e, w64);
        int b = c >> 8;
        int t = atomicAdd(&bcursor[b], 1);
        if (t < BCAP) bucket[(size_t)b * BCAP + t] = ((unsigned)(c & 255) << 20) | (unsigned)r;
    }
}

// one workgroup per bucket: LDS histogram -> offsets+dinv; LDS cursors -> csr fill
// csr writes land in a ~16KB contiguous window -> fully-written lines, no amplification.
__global__ void __launch_bounds__(256)
bucket_csr(const unsigned* __restrict__ bucket, const int* __restrict__ bcnt,
           const int* __restrict__ boff, int n,
           int* __restrict__ offsets, float* __restrict__ dinv, int* __restrict__ csr) {
    __shared__ int hist[256];
    __shared__ int pref[256];
    int b = blockIdx.x;
    int t = threadIdx.x;
    int nbeg = b << 8;
    int cntE = min(bcnt[b], BCAP);
    int base = boff[b];
    const unsigned* __restrict__ bk = bucket + (size_t)b * BCAP;

    hist[t] = 0;
    __syncthreads();
    for (int e = t; e < cntE; e += 256) atomicAdd(&hist[bk[e] >> 20], 1);
    __syncthreads();

    int v = hist[t];
    pref[t] = v;
    __syncthreads();
    for (int off = 1; off < 256; off <<= 1) {
        int tv = (t >= off) ? pref[t - off] : 0;
        __syncthreads();
        pref[t] += tv;
        __syncthreads();
    }
    int myoff = base + pref[t] - v;   // global exclusive offset for node nbeg+t
    if (nbeg + t < n) {
        offsets[nbeg + t] = myoff;
        dinv[nbeg + t] = rsqrtf((float)(v + 1));   // +1 self-loop; deg>=1 always
    }
    hist[t] = 0;          // reuse as per-node cursor
    pref[t] = myoff;      // stash exclusive offset (scan values no longer needed)
    __syncthreads();

    for (int e = t; e < cntE; e += 256) {
        unsigned w = bk[e];
        int l = w >> 20;
        int pos = pref[l] + atomicAdd(&hist[l], 1);
        csr[pos] = (int)(w & 0xFFFFFu);
    }
}

// ---------------- x / W -> packed bf16 ----------------
__global__ void convert_x(const void* __restrict__ xv, unsigned* __restrict__ xb,
                          int total_pairs, const int* __restrict__ flags) {
    int idx = blockIdx.x * blockDim.x + threadIdx.x;
    if (idx >= total_pairs) return;
    if (flags[0]) {
        xb[idx] = ((const unsigned*)xv)[idx];
    } else {
        float2 v = ((const float2*)xv)[idx];
        xb[idx] = pack2bf(v.x, v.y);
    }
}

__global__ void convert_w(const void* __restrict__ Wv, unsigned* __restrict__ Wp,
                          int total_pairs, const int* __restrict__ flags) {
    int idx = blockIdx.x * blockDim.x + threadIdx.x;
    if (idx >= total_pairs) return;
    if (flags[2]) {
        Wp[idx] = ((const unsigned*)Wv)[idx];
    } else {
        float2 v = ((const float2*)Wv)[idx];
        Wp[idx] = pack2bf(v.x, v.y);
    }
}

// ---------------- propagation (bf16 rows, fp32 accumulate, bf16 out) ----------------
// one wave per node; lane = 1 dword = 2 feats (256B/row coalesced). x4 unroll for MLP.
__global__ void propagate_bf16(const unsigned* __restrict__ hin, const int* __restrict__ offsets,
                               const int* __restrict__ csr, const float* __restrict__ dinv,
                               unsigned* __restrict__ hout, int n) {
    int wave = threadIdx.x >> 6;
    int lane = threadIdx.x & 63;
    int i = blockIdx.x * 4 + wave;
    if (i >= n) return;
    int beg = offsets[i];
    int end = offsets[i + 1];
    float di = dinv[i];
    unsigned ps = hin[(size_t)i * 64 + lane];
    float ax = di * bflo(ps);
    float ay = di * bfhi(ps);
    int k = beg;
    for (; k + 3 < end; k += 4) {
        int s0 = csr[k], s1 = csr[k + 1], s2 = csr[k + 2], s3 = csr[k + 3];
        unsigned p0 = hin[(size_t)s0 * 64 + lane];
        unsigned p1 = hin[(size_t)s1 * 64 + lane];
        unsigned p2 = hin[(size_t)s2 * 64 + lane];
        unsigned p3 = hin[(size_t)s3 * 64 + lane];
        float w0 = dinv[s0], w1 = dinv[s1], w2 = dinv[s2], w3 = dinv[s3];
        ax += w0 * bflo(p0); ay += w0 * bfhi(p0);
        ax += w1 * bflo(p1); ay += w1 * bfhi(p1);
        ax += w2 * bflo(p2); ay += w2 * bfhi(p2);
        ax += w3 * bflo(p3); ay += w3 * bfhi(p3);
    }
    for (; k < end; ++k) {
        int s = csr[k];
        unsigned p = hin[(size_t)s * 64 + lane];
        float w = dinv[s];
        ax += w * bflo(p); ay += w * bfhi(p);
    }
    hout[(size_t)i * 64 + lane] = pack2bf(di * ax, di * ay);
}

// ---------------- final linear via MFMA: out = h(n x128) @ W^T(128x64) + b ----------------
// mfma_f32_16x16x32_bf16: wave = 16x16 out tile, K=128 in 4 chunks. (R9: works, off top-5.)
__global__ void __launch_bounds__(256)
final_linear_mfma(const unsigned* __restrict__ hb, const unsigned* __restrict__ Wp,
                  const void* __restrict__ bv, float* __restrict__ out,
                  int n, const int* __restrict__ flags) {
    int wave = threadIdx.x >> 6;     // N-tile index 0..3 (16 cols each)
    int lane = threadIdx.x & 63;
    int m16  = lane & 15;
    int quad = lane >> 4;
    int row0 = blockIdx.x * 16;      // 16 nodes per block
    if (row0 >= n) return;
    int colBase = wave * 16;

    float bo;                        // bias for this lane's column
    if (flags[2]) {
        union { unsigned u; float f; } bc;
        bc.u = ((unsigned)((const unsigned short*)bv)[colBase + m16]) << 16;
        bo = bc.f;
    } else {
        bo = ((const float*)bv)[colBase + m16];
    }

    const uint4* __restrict__ Arow = (const uint4*)(hb + (size_t)(row0 + m16) * 64);
    const uint4* __restrict__ Brow = (const uint4*)(Wp + (size_t)(colBase + m16) * 64);

    floatx4 acc = {0.f, 0.f, 0.f, 0.f};
#pragma unroll
    for (int kc = 0; kc < 4; ++kc) {            // K chunks of 32
        union { uint4 u; short8 s; } a, b;
        a.u = Arow[kc * 4 + quad];              // 8 consecutive bf16 at k = kc*32 + quad*8
        b.u = Brow[kc * 4 + quad];
        acc = __builtin_amdgcn_mfma_f32_16x16x32_bf16(a.s, b.s, acc, 0, 0, 0);
    }
#pragma unroll
    for (int r = 0; r < 4; ++r) {
        int node = row0 + quad * 4 + r;
        out[(size_t)node * OUTF + colBase + m16] = acc[r] + bo;
    }
}

// ---------------- launch ----------------

extern "C" void kernel_launch(void* const* d_in, const int* in_sizes, int n_in,
                              void* d_out, int out_size, void* d_ws, size_t ws_size,
                              hipStream_t stream) {
    const void* x  = d_in[0];
    const int*  ei = (const int*)d_in[1];
    const void* W  = d_in[2];
    const void* b  = d_in[3];
    float* out = (float*)d_out;              // fp32 output (R5/R6 confirmed)

    const int n = in_sizes[0] / FEAT;        // 100000
    const int E = in_sizes[1] / 2;           // 1600000
    const int nbuck = (n + 255) >> 8;        // 391 <= 512

    // workspace layout (256B-aligned slabs); ~94 MB total
    char* ws = (char*)d_ws;
    size_t off = 0;
    auto alloc = [&](size_t bytes) {
        void* p = ws + off;
        off = (off + bytes + 255) & ~(size_t)255;
        return p;
    };
    unsigned* xb      = (unsigned*)alloc((size_t)n * 64 * sizeof(unsigned));  // x as bf16 pairs
    unsigned* hA      = (unsigned*)alloc((size_t)n * 64 * sizeof(unsigned));
    unsigned* hB      = (unsigned*)alloc((size_t)n * 64 * sizeof(unsigned));
    unsigned* Wp      = (unsigned*)alloc((size_t)OUTF * (FEAT / 2) * sizeof(unsigned));
    int*      offsets = (int*)alloc((size_t)(n + 1) * sizeof(int));
    float*    dinv    = (float*)alloc((size_t)n * sizeof(float));
    int*      csr     = (int*)alloc((size_t)E * sizeof(int));
    unsigned* bucket  = (unsigned*)alloc((size_t)nbuck * BCAP * sizeof(unsigned));
    int*      bcnt    = (int*)alloc((size_t)nbuck * sizeof(int));
    int*      bcursor = (int*)alloc((size_t)nbuck * sizeof(int));
    int*      boff    = (int*)alloc((size_t)nbuck * sizeof(int));
    int*      flags   = (int*)alloc(3 * sizeof(int));

    const int edgeBlocks = (E + 255) / 256;

    // dtype sniff (device-side; same work every call, graph-safe)
    sniff<<<1, 256, 0, stream>>>((const unsigned*)x, (const unsigned*)ei,
                                 (const unsigned*)W, flags);

    // CSR build via two-level bucket sort
    zero_buckets<<<(nbuck + 255) / 256, 256, 0, stream>>>(bcnt, bcursor, nbuck);
    bucket_count<<<edgeBlocks, 256, 0, stream>>>(ei, E, bcnt, flags);
    scan_bsums<<<1, 512, 0, stream>>>(bcnt, nbuck, boff, &offsets[n]);
    bucket_scatter<<<edgeBlocks, 256, 0, stream>>>(ei, E, bcursor, bucket, flags);
    bucket_csr<<<nbuck, 256, 0, stream>>>(bucket, bcnt, boff, n, offsets, dinv, csr);

    // x, W -> bf16 packed
    const int totalPairs = n * 64;
    convert_x<<<(totalPairs + 255) / 256, 256, 0, stream>>>(x, xb, totalPairs, flags);
    convert_w<<<(OUTF * FEAT / 2 + 255) / 256, 256, 0, stream>>>(W, Wp, OUTF * FEAT / 2, flags);

    // 3 hops: xb -> A -> B -> A  (bf16 rows, fp32 accum)
    const int propBlocks = (n + 3) / 4;      // 4 waves/block, 1 node/wave
    propagate_bf16<<<propBlocks, 256, 0, stream>>>(xb, offsets, csr, dinv, hA, n);
    propagate_bf16<<<propBlocks, 256, 0, stream>>>(hA, offsets, csr, dinv, hB, n);
    propagate_bf16<<<propBlocks, 256, 0, stream>>>(hB, offsets, csr, dinv, hA, n);

    // final linear via MFMA (fp32 out): 16 nodes/block
    final_linear_mfma<<<(n + 15) / 16, 256, 0, stream>>>(hA, Wp, b, out, n, flags);
}

// Round 11
// 419.580 us; speedup vs baseline: 3.5359x; 3.5359x over previous
//
#include <hip/hip_runtime.h>
#include <hip/hip_bf16.h>

#define FEAT 128
#define OUTF 64
#define BBITS 10          // nodes per bucket = 1024
#define NPB (1 << BBITS)
#define BCAP 20480        // mean 16384 edges/bucket, sigma ~127 -> +32 sigma
#define L1_CHUNK 8192

typedef __attribute__((ext_vector_type(8))) short short8;   // 8 bf16 = 4 VGPRs (MFMA A/B frag)
typedef __attribute__((ext_vector_type(4))) float floatx4;  // MFMA C/D frag

// ---- bf16 helpers (packed pair in a 32-bit word, little-endian: lo16 = even elem) ----
__device__ inline float bflo(unsigned p) { union { unsigned u; float f; } c; c.u = p << 16;        return c.f; }
__device__ inline float bfhi(unsigned p) { union { unsigned u; float f; } c; c.u = p & 0xffff0000u; return c.f; }
__device__ inline unsigned rne16(float v) {   // fp32 -> bf16 bits, round-nearest-even
    union { float f; unsigned u; } c; c.f = v;
    return (c.u + 0x7fffu + ((c.u >> 16) & 1u)) >> 16;
}
__device__ inline unsigned pack2bf(float a, float b) { return rne16(a) | (rne16(b) << 16); }

// ---------------- dtype sniffing ----------------
// flags[0]=1 iff x is packed bf16; flags[1]=1 iff edge_index is int64; flags[2]=1 iff W is packed bf16.
// Established world (R0-R10): x fp32, W bf16, out fp32. Sniffs kept for robustness.
__global__ void sniff(const unsigned* __restrict__ x, const unsigned* __restrict__ ei,
                      const unsigned* __restrict__ Wv, int* __restrict__ flags) {
    __shared__ int s_x, s_z, s_w;
    if (threadIdx.x == 0) { s_x = 0; s_z = 0; s_w = 0; }
    __syncthreads();
    unsigned lx = x[threadIdx.x] & 0xffffu;
    unsigned ex = (lx >> 7) & 0xffu;
    if (lx == 0u || (ex >= 100u && ex <= 140u)) atomicAdd(&s_x, 1);
    unsigned lw = Wv[threadIdx.x] & 0xffffu;
    unsigned ew = (lw >> 7) & 0xffu;
    if (lw == 0u || (ew >= 100u && ew <= 140u)) atomicAdd(&s_w, 1);
    if (ei[2 * threadIdx.x + 1] == 0u) atomicAdd(&s_z, 1);
    __syncthreads();
    if (threadIdx.x == 0) {
        flags[0] = (s_x >= 230) ? 1 : 0;
        flags[1] = (s_z >= 250) ? 1 : 0;
        flags[2] = (s_w >= 230) ? 1 : 0;
    }
}

__device__ inline int edge_row(const int* __restrict__ ei, int E, int e, int w64) {
    return w64 ? ei[2 * e] : ei[e];
}
__device__ inline int edge_col(const int* __restrict__ ei, int E, int e, int w64) {
    return w64 ? ei[2 * (E + e)] : ei[E + e];
}

// ---------------- CSR build: two-level, LDS-binned (R10 post-mortem fix) ----------------
// R10 failure: per-edge global atomics on few counters (558us). Now: per-BLOCK-per-bucket
// tickets (~25K atomics total) + LDS-sorted dense coalesced bucket writes.

__global__ void zero_ints(int* __restrict__ a, int m) {
    int i = blockIdx.x * blockDim.x + threadIdx.x;
    if (i < m) a[i] = 0;
}

// level 1: chunk of 8192 edges per block -> LDS bin-sort by (dst>>10) -> dense copy-out.
// packed word: (dst_local[10] << 17) | src_row[17]   (n < 2^17)
__global__ void __launch_bounds__(256)
level1_bin(const int* __restrict__ ei, int E, int* __restrict__ bcursor,
           unsigned* __restrict__ bucket, const int* __restrict__ flags, int nbuck) {
    __shared__ unsigned elds[L1_CHUNK];
    __shared__ unsigned char ebin[L1_CHUNK];
    __shared__ int hist[128], binstart[128], cur[128], ticket[128];
    int t = threadIdx.x;
    int base = blockIdx.x * L1_CHUNK;
    int cnt = min(E - base, L1_CHUNK);
    int w64 = flags[1];

    if (t < 128) hist[t] = 0;
    __syncthreads();
    for (int k = t; k < cnt; k += 256)
        atomicAdd(&hist[edge_col(ei, E, base + k, w64) >> BBITS], 1);
    __syncthreads();
    if (t < 128) binstart[t] = hist[t];
    __syncthreads();
    for (int off = 1; off < 128; off <<= 1) {
        int v = (t < 128 && t >= off) ? binstart[t - off] : 0;
        __syncthreads();
        if (t < 128) binstart[t] += v;
        __syncthreads();
    }
    if (t < 128) { int ex = binstart[t] - hist[t]; cur[t] = ex; binstart[t] = ex; }
    __syncthreads();
    for (int k = t; k < cnt; k += 256) {
        int e = base + k;
        int c = edge_col(ei, E, e, w64);
        int r = edge_row(ei, E, e, w64);
        int b = c >> BBITS;
        int pos = atomicAdd(&cur[b], 1);
        elds[pos] = ((unsigned)(c & (NPB - 1)) << 17) | (unsigned)r;
        ebin[pos] = (unsigned char)b;
    }
    __syncthreads();
    if (t < 128) {
        int h = hist[t];
        ticket[t] = (t < nbuck && h > 0) ? atomicAdd(&bcursor[t], h) : 0;
    }
    __syncthreads();
    for (int k = t; k < cnt; k += 256) {
        unsigned w = elds[k];
        int b = ebin[k];
        int dst = ticket[b] + (k - binstart[b]);
        if (dst < BCAP) bucket[(size_t)b * BCAP + dst] = w;
    }
}

// single block: exclusive scan of nb (<=512) bucket counts; total -> offsets[n]
__global__ void scan_bsums(const int* __restrict__ bsum, int nb,
                           int* __restrict__ boff, int* __restrict__ total_out) {
    __shared__ int sdata[512];
    int tid = threadIdx.x;
    int v = (tid < nb) ? bsum[tid] : 0;
    sdata[tid] = v;
    __syncthreads();
    for (int off = 1; off < 512; off <<= 1) {
        int t = (tid >= off) ? sdata[tid - off] : 0;
        __syncthreads();
        sdata[tid] += t;
        __syncthreads();
    }
    if (tid < nb) boff[tid] = sdata[tid] - v;       // exclusive
    if (tid == 511) *total_out = sdata[511];        // grand total -> offsets[n]
}

// level 2: one workgroup per bucket (1024 nodes). LDS hist -> offsets+dinv; LDS cursor
// scatter into ~65KB contiguous csr window (L2-resident -> fully-written lines).
__global__ void __launch_bounds__(256)
level2_csr(const unsigned* __restrict__ bucket, const int* __restrict__ bcursor,
           const int* __restrict__ boff, int n,
           int* __restrict__ offsets, float* __restrict__ dinv, int* __restrict__ csr) {
    __shared__ int hist[NPB];
    __shared__ int nodeoff[NPB];
    __shared__ int wsum[256];
    int b = blockIdx.x;
    int t = threadIdx.x;
    int nbeg = b << BBITS;
    int cnt = min(bcursor[b], BCAP);
    int base = boff[b];
    const unsigned* __restrict__ bk = bucket + (size_t)b * BCAP;

    for (int j = t; j < NPB; j += 256) hist[j] = 0;
    __syncthreads();
    for (int e = t; e < cnt; e += 256) atomicAdd(&hist[bk[e] >> 17], 1);
    __syncthreads();
    int h0 = hist[4 * t], h1 = hist[4 * t + 1], h2 = hist[4 * t + 2], h3 = hist[4 * t + 3];
    int s = h0 + h1 + h2 + h3;
    wsum[t] = s;
    __syncthreads();
    for (int off = 1; off < 256; off <<= 1) {
        int v = (t >= off) ? wsum[t - off] : 0;
        __syncthreads();
        wsum[t] += v;
        __syncthreads();
    }
    int p = base + wsum[t] - s;                 // exclusive offset for node 4t
    nodeoff[4 * t]     = p;
    nodeoff[4 * t + 1] = p + h0;
    nodeoff[4 * t + 2] = p + h0 + h1;
    nodeoff[4 * t + 3] = p + h0 + h1 + h2;
    int hs[4] = {h0, h1, h2, h3};
#pragma unroll
    for (int j = 0; j < 4; ++j) {
        int node = nbeg + 4 * t + j;
        if (node < n) {
            offsets[node] = nodeoff[4 * t + j];
            dinv[node] = rsqrtf((float)(hs[j] + 1));   // +1 self-loop; deg>=1 always
        }
    }
    __syncthreads();
    for (int j = t; j < NPB; j += 256) hist[j] = 0;    // reuse as cursors
    __syncthreads();
    for (int e = t; e < cnt; e += 256) {
        unsigned w = bk[e];
        int l = w >> 17;
        int pos = nodeoff[l] + atomicAdd(&hist[l], 1);
        csr[pos] = (int)(w & 0x1FFFFu);
    }
}

// ---------------- x / W -> packed bf16 ----------------
__global__ void convert_x(const void* __restrict__ xv, unsigned* __restrict__ xb,
                          int total_pairs, const int* __restrict__ flags) {
    int idx = blockIdx.x * blockDim.x + threadIdx.x;
    if (idx >= total_pairs) return;
    if (flags[0]) {
        xb[idx] = ((const unsigned*)xv)[idx];
    } else {
        float2 v = ((const float2*)xv)[idx];
        xb[idx] = pack2bf(v.x, v.y);
    }
}

__global__ void convert_w(const void* __restrict__ Wv, unsigned* __restrict__ Wp,
                          int total_pairs, const int* __restrict__ flags) {
    int idx = blockIdx.x * blockDim.x + threadIdx.x;
    if (idx >= total_pairs) return;
    if (flags[2]) {
        Wp[idx] = ((const unsigned*)Wv)[idx];
    } else {
        float2 v = ((const float2*)Wv)[idx];
        Wp[idx] = pack2bf(v.x, v.y);
    }
}

// ---------------- propagation (bf16 rows, fp32 accumulate, bf16 out) ----------------
// one wave per node; lane = 1 dword = 2 feats (256B/row coalesced). x4 unroll for MLP.
__global__ void propagate_bf16(const unsigned* __restrict__ hin, const int* __restrict__ offsets,
                               const int* __restrict__ csr, const float* __restrict__ dinv,
                               unsigned* __restrict__ hout, int n) {
    int wave = threadIdx.x >> 6;
    int lane = threadIdx.x & 63;
    int i = blockIdx.x * 4 + wave;
    if (i >= n) return;
    int beg = offsets[i];
    int end = offsets[i + 1];
    float di = dinv[i];
    unsigned ps = hin[(size_t)i * 64 + lane];
    float ax = di * bflo(ps);
    float ay = di * bfhi(ps);
    int k = beg;
    for (; k + 3 < end; k += 4) {
        int s0 = csr[k], s1 = csr[k + 1], s2 = csr[k + 2], s3 = csr[k + 3];
        unsigned p0 = hin[(size_t)s0 * 64 + lane];
        unsigned p1 = hin[(size_t)s1 * 64 + lane];
        unsigned p2 = hin[(size_t)s2 * 64 + lane];
        unsigned p3 = hin[(size_t)s3 * 64 + lane];
        float w0 = dinv[s0], w1 = dinv[s1], w2 = dinv[s2], w3 = dinv[s3];
        ax += w0 * bflo(p0); ay += w0 * bfhi(p0);
        ax += w1 * bflo(p1); ay += w1 * bfhi(p1);
        ax += w2 * bflo(p2); ay += w2 * bfhi(p2);
        ax += w3 * bflo(p3); ay += w3 * bfhi(p3);
    }
    for (; k < end; ++k) {
        int s = csr[k];
        unsigned p = hin[(size_t)s * 64 + lane];
        float w = dinv[s];
        ax += w * bflo(p); ay += w * bfhi(p);
    }
    hout[(size_t)i * 64 + lane] = pack2bf(di * ax, di * ay);
}

// ---------------- final linear via MFMA: out = h(n x128) @ W^T(128x64) + b ----------------
// mfma_f32_16x16x32_bf16: wave = 16x16 out tile, K=128 in 4 chunks. (R9: works, ~15us.)
__global__ void __launch_bounds__(256)
final_linear_mfma(const unsigned* __restrict__ hb, const unsigned* __restrict__ Wp,
                  const void* __restrict__ bv, float* __restrict__ out,
                  int n, const int* __restrict__ flags) {
    int wave = threadIdx.x >> 6;     // N-tile index 0..3 (16 cols each)
    int lane = threadIdx.x & 63;
    int m16  = lane & 15;
    int quad = lane >> 4;
    int row0 = blockIdx.x * 16;      // 16 nodes per block
    if (row0 >= n) return;
    int colBase = wave * 16;

    float bo;                        // bias for this lane's column
    if (flags[2]) {
        union { unsigned u; float f; } bc;
        bc.u = ((unsigned)((const unsigned short*)bv)[colBase + m16]) << 16;
        bo = bc.f;
    } else {
        bo = ((const float*)bv)[colBase + m16];
    }

    const uint4* __restrict__ Arow = (const uint4*)(hb + (size_t)(row0 + m16) * 64);
    const uint4* __restrict__ Brow = (const uint4*)(Wp + (size_t)(colBase + m16) * 64);

    floatx4 acc = {0.f, 0.f, 0.f, 0.f};
#pragma unroll
    for (int kc = 0; kc < 4; ++kc) {            // K chunks of 32
        union { uint4 u; short8 s; } a, b;
        a.u = Arow[kc * 4 + quad];              // 8 consecutive bf16 at k = kc*32 + quad*8
        b.u = Brow[kc * 4 + quad];
        acc = __builtin_amdgcn_mfma_f32_16x16x32_bf16(a.s, b.s, acc, 0, 0, 0);
    }
#pragma unroll
    for (int r = 0; r < 4; ++r) {
        int node = row0 + quad * 4 + r;
        out[(size_t)node * OUTF + colBase + m16] = acc[r] + bo;
    }
}

// ---------------- launch ----------------

extern "C" void kernel_launch(void* const* d_in, const int* in_sizes, int n_in,
                              void* d_out, int out_size, void* d_ws, size_t ws_size,
                              hipStream_t stream) {
    const void* x  = d_in[0];
    const int*  ei = (const int*)d_in[1];
    const void* W  = d_in[2];
    const void* b  = d_in[3];
    float* out = (float*)d_out;              // fp32 output (R5/R6 confirmed)

    const int n = in_sizes[0] / FEAT;        // 100000
    const int E = in_sizes[1] / 2;           // 1600000
    const int nbuck = (n + NPB - 1) >> BBITS;   // 98 <= 128

    // workspace layout (256B-aligned slabs); ~68 MB total
    char* ws = (char*)d_ws;
    size_t off = 0;
    auto alloc = [&](size_t bytes) {
        void* p = ws + off;
        off = (off + bytes + 255) & ~(size_t)255;
        return p;
    };
    unsigned* xb      = (unsigned*)alloc((size_t)n * 64 * sizeof(unsigned));  // x as bf16 pairs
    unsigned* hA      = (unsigned*)alloc((size_t)n * 64 * sizeof(unsigned));
    unsigned* hB      = (unsigned*)alloc((size_t)n * 64 * sizeof(unsigned));
    unsigned* Wp      = (unsigned*)alloc((size_t)OUTF * (FEAT / 2) * sizeof(unsigned));
    int*      offsets = (int*)alloc((size_t)(n + 1) * sizeof(int));
    float*    dinv    = (float*)alloc((size_t)n * sizeof(float));
    int*      csr     = (int*)alloc((size_t)E * sizeof(int));
    unsigned* bucket  = (unsigned*)alloc((size_t)nbuck * BCAP * sizeof(unsigned));
    int*      bcursor = (int*)alloc((size_t)nbuck * sizeof(int));
    int*      boff    = (int*)alloc((size_t)nbuck * sizeof(int));
    int*      flags   = (int*)alloc(3 * sizeof(int));

    // dtype sniff (device-side; same work every call, graph-safe)
    sniff<<<1, 256, 0, stream>>>((const unsigned*)x, (const unsigned*)ei,
                                 (const unsigned*)W, flags);

    // CSR build: LDS-binned two-level
    zero_ints<<<1, 256, 0, stream>>>(bcursor, nbuck);
    level1_bin<<<(E + L1_CHUNK - 1) / L1_CHUNK, 256, 0, stream>>>(ei, E, bcursor, bucket,
                                                                  flags, nbuck);
    scan_bsums<<<1, 512, 0, stream>>>(bcursor, nbuck, boff, &offsets[n]);
    level2_csr<<<nbuck, 256, 0, stream>>>(bucket, bcursor, boff, n, offsets, dinv, csr);

    // x, W -> bf16 packed
    const int totalPairs = n * 64;
    convert_x<<<(totalPairs + 255) / 256, 256, 0, stream>>>(x, xb, totalPairs, flags);
    convert_w<<<(OUTF * FEAT / 2 + 255) / 256, 256, 0, stream>>>(W, Wp, OUTF * FEAT / 2, flags);

    // 3 hops: xb -> A -> B -> A  (bf16 rows, fp32 accum)
    const int propBlocks = (n + 3) / 4;      // 4 waves/block, 1 node/wave
    propagate_bf16<<<propBlocks, 256, 0, stream>>>(xb, offsets, csr, dinv, hA, n);
    propagate_bf16<<<propBlocks, 256, 0, stream>>>(hA, offsets, csr, dinv, hB, n);
    propagate_bf16<<<propBlocks, 256, 0, stream>>>(hB, offsets, csr, dinv, hA, n);

    // final linear via MFMA (fp32 out): 16 nodes/block
    final_linear_mfma<<<(n + 15) / 16, 256, 0, stream>>>(hA, Wp, b, out, n, flags);
}